// Round 8
// baseline (870.817 us; speedup 1.0000x reference)
//
#include <hip/hip_runtime.h>
#include <hip/hip_bf16.h>
#include <math.h>

// Problem constants (match reference)
#define BB 8
#define SS 2048
#define DD 1024
#define DS 64
#define MM (BB*SS)   // 16384

// ---------------- helpers ----------------

__device__ __forceinline__ float4 ld4(const float* p) { return *(const float4*)p; }

template<int CTRL>
__device__ __forceinline__ float dppadd(float x) {
  int v = __builtin_amdgcn_update_dpp(0, __float_as_int(x), CTRL, 0xf, 0xf, true);
  return x + __int_as_float(v);
}

// xor-16 / xor-32 butterfly-add stages via gfx950 permlane swaps (pure VALU).
__device__ __forceinline__ float xor16add(float x) {
#if defined(__has_builtin) && __has_builtin(__builtin_amdgcn_permlane16_swap)
  auto r = __builtin_amdgcn_permlane16_swap(__float_as_uint(x), __float_as_uint(x), false, false);
  return __uint_as_float(r[0]) + __uint_as_float(r[1]);
#else
  return x + __shfl_xor(x, 16, 64);
#endif
}
__device__ __forceinline__ float xor32add(float x) {
#if defined(__has_builtin) && __has_builtin(__builtin_amdgcn_permlane32_swap)
  auto r = __builtin_amdgcn_permlane32_swap(__float_as_uint(x), __float_as_uint(x), false, false);
  return __uint_as_float(r[0]) + __uint_as_float(r[1]);
#else
  return x + __shfl_xor(x, 32, 64);
#endif
}

// full 64-lane butterfly sum; result valid in all lanes
__device__ __forceinline__ float wsum(float x) {
  x = dppadd<0xB1>(x);   // quad_perm xor1
  x = dppadd<0x4E>(x);   // quad_perm xor2
  x = dppadd<0x141>(x);  // row_half_mirror (completes 8-group)
  x = dppadd<0x140>(x);  // row_mirror      (completes 16-group)
  x = xor16add(x);
  x = xor32add(x);
  return x;
}

__device__ __forceinline__ float gelu_exact(float x) {
  return 0.5f * x * (1.f + erff(x * 0.7071067811865476f));
}

// global -> LDS async staging (data lands at LDS base + lane*size)
__device__ __forceinline__ void gll16(const float* g, float* l) {
  __builtin_amdgcn_global_load_lds(
      (const __attribute__((address_space(1))) void*)g,
      (__attribute__((address_space(3))) void*)l, 16, 0, 0);
}
__device__ __forceinline__ void gll4(const float* g, float* l) {
  __builtin_amdgcn_global_load_lds(
      (const __attribute__((address_space(1))) void*)g,
      (__attribute__((address_space(3))) void*)l, 4, 0, 0);
}

// ---------------- k0: pack weights [Wk;Wv;Wq;ir_w1;pw;0-pad] -> Wcat[320][1024]
__global__ __launch_bounds__(256) void pack_w(
    const float* __restrict__ Wk, const float* __restrict__ Wv,
    const float* __restrict__ Wq, const float* __restrict__ ir_w1,
    const float* __restrict__ pw, float* __restrict__ Wcat) {
  int idx = blockIdx.x * 256 + threadIdx.x;   // 320*1024 total
  int r = idx >> 10, c = idx & 1023;
  float val = 0.f;
  if (r < 64)       val = Wk[r*1024 + c];
  else if (r < 128) val = Wv[(r-64)*1024 + c];
  else if (r < 192) val = Wq[(r-128)*1024 + c];
  else if (r < 256) val = ir_w1[(r-192)*1024 + c];
  else if (r < 259) val = pw[(r-256)*1024 + c];
  Wcat[idx] = val;
}

// ---------------- k1: Y[16384][320] = X[16384][1024] @ Wcat[320][1024]^T
__global__ __launch_bounds__(256) void gemm1(
    const float* __restrict__ X, const float* __restrict__ Wcat,
    float* __restrict__ Y) {
  __shared__ float As[32*128];   // [k][m]
  __shared__ float Bs[32*64];    // [k][n]
  const int t  = threadIdx.x;
  const int m0 = blockIdx.x * 128;
  const int n0 = blockIdx.y * 64;
  const int mi = t >> 4, ni = t & 15;
  const int rA = t >> 1, hA = t & 1;
  const int rB = t >> 2, qB = t & 3;
  float acc[8][4];
  #pragma unroll
  for (int i = 0; i < 8; ++i)
    #pragma unroll
    for (int j = 0; j < 4; ++j) acc[i][j] = 0.f;

  for (int k0 = 0; k0 < 1024; k0 += 32) {
    __syncthreads();
    {
      const float* src = X + (size_t)(m0 + rA)*1024 + k0 + hA*16;
      #pragma unroll
      for (int jj = 0; jj < 4; ++jj) {
        float4 xv = ld4(src + jj*4);
        int kk = hA*16 + jj*4;
        As[(kk+0)*128 + rA] = xv.x; As[(kk+1)*128 + rA] = xv.y;
        As[(kk+2)*128 + rA] = xv.z; As[(kk+3)*128 + rA] = xv.w;
      }
      const float* srcB = Wcat + (size_t)(n0 + rB)*1024 + k0 + qB*8;
      #pragma unroll
      for (int jj = 0; jj < 2; ++jj) {
        float4 bv = ld4(srcB + jj*4);
        int kb = qB*8 + jj*4;
        Bs[(kb+0)*64 + rB] = bv.x; Bs[(kb+1)*64 + rB] = bv.y;
        Bs[(kb+2)*64 + rB] = bv.z; Bs[(kb+3)*64 + rB] = bv.w;
      }
    }
    __syncthreads();
    #pragma unroll
    for (int kk = 0; kk < 32; ++kk) {
      float a[8], bv[4];
      float4 a0 = *(const float4*)&As[kk*128 + mi*8];
      float4 a1 = *(const float4*)&As[kk*128 + mi*8 + 4];
      float4 b0 = *(const float4*)&Bs[kk*64 + ni*4];
      a[0]=a0.x; a[1]=a0.y; a[2]=a0.z; a[3]=a0.w;
      a[4]=a1.x; a[5]=a1.y; a[6]=a1.z; a[7]=a1.w;
      bv[0]=b0.x; bv[1]=b0.y; bv[2]=b0.z; bv[3]=b0.w;
      #pragma unroll
      for (int im = 0; im < 8; ++im)
        #pragma unroll
        for (int in = 0; in < 4; ++in)
          acc[im][in] = fmaf(a[im], bv[in], acc[im][in]);
    }
  }
  #pragma unroll
  for (int im = 0; im < 8; ++im) {
    float4 o; o.x = acc[im][0]; o.y = acc[im][1]; o.z = acc[im][2]; o.w = acc[im][3];
    *(float4*)&Y[(size_t)(m0 + mi*8 + im)*320 + n0 + ni*4] = o;
  }
}

// ---------------- k2: per-token postprocess -> K,V,Q,NU,PW, SCL12[0..3]
__global__ __launch_bounds__(256) void post_kernel(
    const float* __restrict__ Y,
    const float* __restrict__ nm_w1, const float* __restrict__ nm_b1,
    const float* __restrict__ nm_w2, const float* __restrict__ nm_b2,
    const float* __restrict__ ir_b1, const float* __restrict__ ir_w2,
    const float* __restrict__ ir_b2, const float* __restrict__ sap,
    float* __restrict__ K, float* __restrict__ V, float* __restrict__ Q,
    float* __restrict__ NU, float* __restrict__ PW,
    float* __restrict__ SCL12) {
  __shared__ float w1s[128*65];
  __shared__ float w2s[64*129];
  __shared__ float vbuf[4][64];
  __shared__ float h1buf[4][128];
  const int tid = threadIdx.x, wid = tid >> 6, l = tid & 63;
  for (int i = tid; i < 128*64; i += 256) w1s[(i>>6)*65 + (i&63)]  = nm_w1[i];
  for (int i = tid; i < 64*128; i += 256) w2s[(i>>7)*129 + (i&127)] = nm_w2[i];
  __syncthreads();
  const float sa   = *sap;
  const float b1a  = nm_b1[l], b1b = nm_b1[64+l], b2l = nm_b2[l];
  const float irb1 = ir_b1[l], irw2 = ir_w2[l],  irb2 = ir_b2[0];
  for (int r = 0; r < 4; ++r) {
    const int tok = blockIdx.x*16 + r*4 + wid;
    const float* yr = Y + (size_t)tok*320;
    float kr = yr[l], vr = yr[64+l], qr = yr[128+l], hr = yr[192+l];
    float rk = 1.f / fmaxf(sqrtf(wsum(kr*kr)), 1e-12f);
    float rq = 1.f / fmaxf(sqrtf(wsum(qr*qr)), 1e-12f);
    float kn = kr*rk, qn = qr*rq;
    float qk = wsum(kn*qn);
    float g  = gelu_exact(hr + irb1);
    float logit = wsum(g*irw2) + irb2;
    float imp = 1.f/(1.f+expf(-logit));
    float bs  = (imp > 0.5f) ? (1.f - sa) : 0.f;   // (1-slow_alpha)*u_slow
    K[(size_t)tok*64+l] = kn; V[(size_t)tok*64+l] = vr; Q[(size_t)tok*64+l] = qn;
    vbuf[wid][l] = vr;
    __syncthreads();
    float h1a = b1a, h1b = b1b;
    #pragma unroll 8
    for (int c = 0; c < 64; ++c) {
      float vv = vbuf[wid][c];
      h1a = fmaf(w1s[l*65 + c], vv, h1a);
      h1b = fmaf(w1s[(64+l)*65 + c], vv, h1b);
    }
    h1buf[wid][l]    = gelu_exact(h1a);
    h1buf[wid][64+l] = gelu_exact(h1b);
    __syncthreads();
    float nu = b2l;
    #pragma unroll 8
    for (int j = 0; j < 128; ++j) nu = fmaf(w2s[l*129 + j], h1buf[wid][j], nu);
    NU[(size_t)tok*64+l] = nu;
    float p0 = yr[256], p1 = yr[257], p2 = yr[258];
    float mx = fmaxf(p0, fmaxf(p1, p2));
    float e0 = expf(p0-mx), e1 = expf(p1-mx), e2 = expf(p2-mx);
    float inv = 1.f/(e0+e1+e2);
    if (l == 0) {
      PW[(size_t)tok*3]   = e0*inv;
      float4 s; s.x = qk; s.y = bs; s.z = e0*inv; s.w = e1*inv;
      *(float4*)&SCL12[(size_t)tok*12] = s;
    }
    else if (l == 1)   PW[(size_t)tok*3+1] = e1*inv;
    else if (l == 2)   PW[(size_t)tok*3+2] = e2*inv;
    __syncthreads();
  }
}

// ---------------- k2b: V[b][t][v] -> VT[b][v][t] (64x64 LDS tiles)
__global__ __launch_bounds__(256) void transpose_v(
    const float* __restrict__ V, float* __restrict__ VT) {
  __shared__ float tile[64][65];
  const int b  = blockIdx.x >> 5;
  const int t0 = (blockIdx.x & 31) * 64;
  const int tid = threadIdx.x;
  const int rr = tid >> 6, cc = tid & 63;
  #pragma unroll
  for (int r4 = 0; r4 < 64; r4 += 4) {
    int t = t0 + r4 + rr;
    tile[r4 + rr][cc] = V[((size_t)b*SS + t)*64 + cc];
  }
  __syncthreads();
  #pragma unroll
  for (int r4 = 0; r4 < 64; r4 += 4) {
    int vv = r4 + rr;
    VT[((size_t)b*64 + vv)*SS + t0 + cc] = tile[cc][vv];
  }
}

// ---------------- k2c: cross-token dots -> SCL12[4+j-1]=k_t.k_{t-j},
//                       SCL12[8+j-1]=q_t.k_{t-j}, j=1..4
__global__ __launch_bounds__(256) void crossdot_kernel(
    const float* __restrict__ K, const float* __restrict__ Q,
    float* __restrict__ SCL12) {
  const int tok = blockIdx.x*4 + (threadIdx.x >> 6);
  const int l = threadIdx.x & 63;
  const int tloc = tok & (SS-1);
  const float kt = K[(size_t)tok*64 + l];
  const float qt = Q[(size_t)tok*64 + l];
  float kk[4], qk[4];
  #pragma unroll
  for (int j = 1; j <= 4; ++j) {
    float kp = (tloc >= j) ? K[(size_t)(tok-j)*64 + l] : 0.f;
    kk[j-1] = wsum(kt*kp);
    qk[j-1] = wsum(qt*kp);
  }
  if (l == 0) {
    float4 a; a.x=kk[0]; a.y=kk[1]; a.z=kk[2]; a.w=kk[3];
    float4 b; b.x=qk[0]; b.y=qk[1]; b.z=qk[2]; b.w=qk[3];
    *(float4*)&SCL12[(size_t)tok*12 + 4] = a;
    *(float4*)&SCL12[(size_t)tok*12 + 8] = b;
  }
}

// ---------------- k3: sequential scan, column-parallel, D=4 WY-deferred,
// all per-step operands pre-staged into register rings.
// One wave per (b, v). Lane l holds fH[l][v], sH[l][v].
//   pf_t = fa^4*(k_t.fH_{t-5}) + sum_{j=1..4} fa^{j-1}*gf_{t-j}*(k_t.k_{t-j})
// dff for token t is launched (4 wsums) at step t-4 reading fH_{t-5}; the
// cross-dots kk_j/qk_j are precomputed. k/q ring prefetch +6 steps, v/scalars
// +2 steps -> no in-step LDS latency on the critical path.
#define CH 64
__global__ __launch_bounds__(64) void scan_kernel(
    const float* __restrict__ K, const float* __restrict__ Q,
    const float* __restrict__ VT, const float* __restrict__ SCL12,
    const float* __restrict__ fap, const float* __restrict__ sap,
    float* __restrict__ OBASE, float* __restrict__ E) {
  __shared__ float lK[2][CH*64];   // 32 KB
  __shared__ float lQ[2][CH*64];   // 32 KB
  __shared__ float lV[2][CH];      // 512 B
  __shared__ float lS[2][CH*12];   // 6 KB
  const int b = blockIdx.x >> 6;
  const int v = blockIdx.x & 63;
  const int l = threadIdx.x;
  const float fa = *fap, sa = *sap, omfa = 1.f - fa;
  const float fa2 = fa*fa, fa3 = fa2*fa, fa4 = fa2*fa2;
  const float sa2 = sa*sa, sa3 = sa2*sa, sa4 = sa2*sa2;
  const size_t base = (size_t)b * SS * 64;
  const float* gK = K + base + l*4;
  const float* gQ = Q + base + l*4;
  const float* gV = VT + ((size_t)b*64 + v)*SS + l;
  const float* gS = SCL12 + (size_t)b*SS*12 + l*4;
  float* stp = ((l == 32) ? E : OBASE) + base + v;

  float fH = 0.f, sH = 0.f;
  float dff[8] = {0.f}, dqf[8] = {0.f}, dss[8] = {0.f}, dqs[8] = {0.f};
  float kv[8], qv[8];
  float vv[2];
  float4 sv0[2], skk[2], sqk[2];
  float gfh1=0.f, gfh2=0.f, gfh3=0.f, gfh4=0.f;
  float gsh1=0.f, gsh2=0.f, gsh3=0.f, gsh4=0.f;

#define STAGE(buf, c) {                                              \
    const float* kc_ = gK + (size_t)(c)*CH*64;                       \
    const float* qc_ = gQ + (size_t)(c)*CH*64;                       \
    _Pragma("unroll")                                                \
    for (int j = 0; j < 16; ++j) {                                   \
      gll16(kc_ + j*256, &lK[buf][j*256]);                           \
      gll16(qc_ + j*256, &lQ[buf][j*256]);                           \
    }                                                                \
    gll4(gV + (size_t)(c)*CH, &lV[buf][0]);                          \
    _Pragma("unroll")                                                \
    for (int j = 0; j < 3; ++j)                                      \
      gll16(gS + (size_t)(c)*CH*12 + j*256, &lS[buf][j*256]); }

#define VMDRAIN { asm volatile("s_waitcnt vmcnt(0)" ::: "memory");   \
                  __builtin_amdgcn_sched_barrier(0); }

  // Step T (chunk-local, compile-time). CURB/NXTB runtime buffer indices.
#define STEPX(T, CURB, NXTB, VALX) {                                 \
    constexpr int i_ = (T) & 7;                                      \
    constexpr int p_ = (T) & 1;                                      \
    /* 1) launch 4 wsums for token T+4 (reads fH_{T-1}, sH_{T-1}) */ \
    const float kn_ = kv[(i_+4)&7], qn_ = qv[(i_+4)&7];              \
    const float ndff = wsum(kn_*fH), ndqf = wsum(qn_*fH);            \
    const float ndss = wsum(kn_*sH), ndqs = wsum(qn_*sH);            \
    /* 2) consume rings */                                           \
    const float  vc  = vv[p_];                                       \
    const float4 sc  = sv0[p_];                                      \
    const float4 kk4 = skk[p_];                                      \
    const float4 qk4 = sqk[p_];                                      \
    /* 3) ring prefetches (k/q +6, v/s +2) */                        \
    { constexpr int tk = (T) + 6;                                    \
      if constexpr (tk < CH) {                                       \
        kv[(i_+6)&7] = lK[CURB][tk*64 + l];                          \
        qv[(i_+6)&7] = lQ[CURB][tk*64 + l];                          \
      } else {                                                       \
        kv[(i_+6)&7] = lK[NXTB][(tk-CH)*64 + l];                     \
        qv[(i_+6)&7] = lQ[NXTB][(tk-CH)*64 + l];                     \
      } }                                                            \
    { constexpr int tv = (T) + 2;                                    \
      if constexpr (tv < CH) {                                       \
        vv[p_]  = lV[CURB][tv];                                      \
        sv0[p_] = *(const float4*)&lS[CURB][tv*12];                  \
        skk[p_] = *(const float4*)&lS[CURB][tv*12 + 4];              \
        sqk[p_] = *(const float4*)&lS[CURB][tv*12 + 8];              \
      } else {                                                       \
        vv[p_]  = lV[NXTB][tv-CH];                                   \
        sv0[p_] = *(const float4*)&lS[NXTB][(tv-CH)*12];             \
        skk[p_] = *(const float4*)&lS[NXTB][(tv-CH)*12 + 4];         \
        sqk[p_] = *(const float4*)&lS[NXTB][(tv-CH)*12 + 8];         \
      } }                                                            \
    /* 4) deferred projections + corrections */                      \
    const float a2 = fa*gfh2, a3 = fa2*gfh3, a4 = fa3*gfh4;          \
    const float b2 = sa*gsh2, b3 = sa2*gsh3, b4 = sa3*gsh4;          \
    const float cf  = fmaf(a2, kk4.y, fmaf(a3, kk4.z, a4*kk4.w));    \
    const float cq  = fmaf(a2, qk4.y, fmaf(a3, qk4.z, a4*qk4.w));    \
    const float cs  = fmaf(b2, kk4.y, fmaf(b3, kk4.z, b4*kk4.w));    \
    const float cqs = fmaf(b2, qk4.y, fmaf(b3, qk4.z, b4*qk4.w));    \
    const float pf  = fmaf(fa4, dff[i_], fmaf(gfh1, kk4.x, cf));     \
    const float pq  = fmaf(fa4, dqf[i_], fmaf(gfh1, qk4.x, cq));     \
    const float ps  = fmaf(sa4, dss[i_], fmaf(gsh1, kk4.x, cs));     \
    const float pqs = fmaf(sa4, dqs[i_], fmaf(gsh1, qk4.x, cqs));    \
    const float gf = omfa*(vc - pf);                                 \
    const float gs = sc.y*(vc - ps);                                 \
    const float qfn = fmaf(gf, sc.x, fa*pq);                         \
    const float qsn = fmaf(gs, sc.x, sa*pqs);                        \
    const float pd = vc - 0.5f*(pq + pqs);                           \
    VALX = (l == 32) ? pd*pd : fmaf(sc.z, qfn, sc.w*qsn);            \
    fH = fmaf(gf, kv[i_], fa*fH);                                    \
    sH = fmaf(gs, kv[i_], sa*sH);                                    \
    gfh4=gfh3; gfh3=gfh2; gfh2=gfh1; gfh1=gf;                        \
    gsh4=gsh3; gsh3=gsh2; gsh2=gsh1; gsh1=gs;                        \
    dff[(i_+4)&7]=ndff; dqf[(i_+4)&7]=ndqf;                          \
    dss[(i_+4)&7]=ndss; dqs[(i_+4)&7]=ndqs; }

#define BODY8(T0, CURB, NXTB) {                                      \
    float val[8];                                                    \
    STEPX(T0+0, CURB, NXTB, val[0]) STEPX(T0+1, CURB, NXTB, val[1])  \
    STEPX(T0+2, CURB, NXTB, val[2]) STEPX(T0+3, CURB, NXTB, val[3])  \
    STEPX(T0+4, CURB, NXTB, val[4]) STEPX(T0+5, CURB, NXTB, val[5])  \
    STEPX(T0+6, CURB, NXTB, val[6]) STEPX(T0+7, CURB, NXTB, val[7])  \
    if (l == 0 || l == 32) {                                         \
      _Pragma("unroll")                                              \
      for (int z = 0; z < 8; ++z)                                    \
        stp[(size_t)(cbase + (T0) + z)*64] = val[z];                 \
    } }

  STAGE(0, 0)
  VMDRAIN
  // prime register rings from chunk 0
  #pragma unroll
  for (int j = 0; j < 6; ++j) { kv[j] = lK[0][j*64 + l]; qv[j] = lQ[0][j*64 + l]; }
  #pragma unroll
  for (int j = 0; j < 2; ++j) {
    vv[j]  = lV[0][j];
    sv0[j] = *(const float4*)&lS[0][j*12];
    skk[j] = *(const float4*)&lS[0][j*12 + 4];
    sqk[j] = *(const float4*)&lS[0][j*12 + 8];
  }
  int cur = 0;
  for (int c = 0; c < 32; ++c) {
    const int cbase = c*CH;
    const int nxt = cur ^ 1;
    if (c + 1 < 32) STAGE(nxt, c + 1)
    BODY8( 0, cur, nxt) BODY8( 8, cur, nxt)
    BODY8(16, cur, nxt) BODY8(24, cur, nxt)
    BODY8(32, cur, nxt) BODY8(40, cur, nxt)
    BODY8(48, cur, nxt)
    VMDRAIN              // next chunk resident before boundary prefetches
    BODY8(56, cur, nxt)
    cur = nxt;
  }
#undef STAGE
#undef VMDRAIN
#undef STEPX
#undef BODY8
}

// ---------------- k4: err reduce -> ns-gate coefficient c = 0.1*u_neu
__global__ __launch_bounds__(256) void err_kernel(
    const float* __restrict__ E, float* __restrict__ CNS) {
  int row = blockIdx.x*4 + (threadIdx.x >> 6);
  int l = threadIdx.x & 63;
  float s = wsum(E[(size_t)row*64 + l]);
  if (l == 0) {
    float z = s / (1.0f + 1e-6f);          // TEMP + 1e-6
    float sg = 1.f/(1.f+expf(-z));
    CNS[row] = (sg > 0.7f) ? 0.1f : 0.f;
  }
}

// ---------------- k5: ns scan + o assembly, software-pipelined
#define BW 16
__device__ __forceinline__ void loadw(int b, int t0, int v,
    const float* __restrict__ CNS, const float* __restrict__ NU,
    const float* __restrict__ OBASE, const float* __restrict__ PW,
    float* c, float* nu, float* ob, float* p2) {
  #pragma unroll
  for (int i = 0; i < BW; ++i) {
    size_t bt = (size_t)b*SS + (t0 + i);
    c[i]  = CNS[bt];
    nu[i] = NU[bt*64 + v];
    ob[i] = OBASE[bt*64 + v];
    p2[i] = PW[bt*3 + 2];
  }
}
__device__ __forceinline__ float procw(int b, int t0, int v, float ns,
    const float* c, const float* nu, const float* ob, const float* p2,
    float* __restrict__ OB) {
  #pragma unroll
  for (int i = 0; i < BW; ++i) {
    float cn = c[i]*nu[i];
    float a  = 1.f - c[i];
    ns = fmaf(a, ns, cn);                 // ns = (1-c)*ns + c*nu
    float o = fmaf(p2[i], ns, ob[i]);
    OB[((size_t)b*SS + (t0+i))*64 + v] = o;
  }
  return ns;
}
__global__ __launch_bounds__(64) void nsout_kernel(
    const float* __restrict__ CNS, const float* __restrict__ NU,
    const float* __restrict__ OBASE, const float* __restrict__ PW,
    float* __restrict__ OB) {
  const int b = blockIdx.x, v = threadIdx.x;
  float cA[BW],nA[BW],oA[BW],pA[BW], cB[BW],nB[BW],oB[BW],pB[BW];
  loadw(b, 0, v, CNS, NU, OBASE, PW, cA, nA, oA, pA);
  float ns = 0.f;
  for (int t0 = 0; t0 < SS; t0 += 2*BW) {
    int tB = t0 + BW;
    loadw(b, tB, v, CNS, NU, OBASE, PW, cB, nB, oB, pB);
    ns = procw(b, t0, v, ns, cA, nA, oA, pA, OB);
    int tA2 = t0 + 2*BW; if (tA2 > SS - BW) tA2 = SS - BW;
    loadw(b, tA2, v, CNS, NU, OBASE, PW, cA, nA, oA, pA);
    ns = procw(b, tB, v, ns, cB, nB, oB, pB, OB);
  }
}

// ---------------- k6: fused RMSNorm + out = normed @ Wo^T
__global__ __launch_bounds__(256) void out_gemm(
    const float* __restrict__ OB, const float* __restrict__ Wo,
    const float* __restrict__ normw, float* __restrict__ out) {
  __shared__ float As[64*64];    // [k][m]
  __shared__ float Bs[64*128];   // [k][n]
  const int t  = threadIdx.x;
  const int m0 = blockIdx.y * 64;
  const int n0 = blockIdx.x * 128;
  {
    int r = t >> 2, q4 = t & 3;
    const float* src = OB + (size_t)(m0 + r)*64 + q4*16;
    float4 x0 = ld4(src), x1 = ld4(src+4), x2 = ld4(src+8), x3 = ld4(src+12);
    float ss = x0.x*x0.x+x0.y*x0.y+x0.z*x0.z+x0.w*x0.w
             + x1.x*x1.x+x1.y*x1.y+x1.z*x1.z+x1.w*x1.w
             + x2.x*x2.x+x2.y*x2.y+x2.z*x2.z+x2.w*x2.w
             + x3.x*x3.x+x3.y*x3.y+x3.z*x3.z+x3.w*x3.w;
    ss += __shfl_xor(ss, 1, 64);
    ss += __shfl_xor(ss, 2, 64);
    float rms = rsqrtf(ss * (1.f/64.f) + 1e-6f);
    const float* nw = normw + q4*16;
    float4 w0 = ld4(nw), w1 = ld4(nw+4), w2 = ld4(nw+8), w3 = ld4(nw+12);
    int kbase = q4*16;
    As[(kbase+ 0)*64+r]=x0.x*rms*w0.x; As[(kbase+ 1)*64+r]=x0.y*rms*w0.y;
    As[(kbase+ 2)*64+r]=x0.z*rms*w0.z; As[(kbase+ 3)*64+r]=x0.w*rms*w0.w;
    As[(kbase+ 4)*64+r]=x1.x*rms*w1.x; As[(kbase+ 5)*64+r]=x1.y*rms*w1.y;
    As[(kbase+ 6)*64+r]=x1.z*rms*w1.z; As[(kbase+ 7)*64+r]=x1.w*rms*w1.w;
    As[(kbase+ 8)*64+r]=x2.x*rms*w2.x; As[(kbase+ 9)*64+r]=x2.y*rms*w2.y;
    As[(kbase+10)*64+r]=x2.z*rms*w2.z; As[(kbase+11)*64+r]=x2.w*rms*w2.w;
    As[(kbase+12)*64+r]=x3.x*rms*w3.x; As[(kbase+13)*64+r]=x3.y*rms*w3.y;
    As[(kbase+14)*64+r]=x3.z*rms*w3.z; As[(kbase+15)*64+r]=x3.w*rms*w3.w;
  }
  {
    int rw = t >> 1, half = t & 1;
    const float* src = Wo + (size_t)(n0 + rw)*64 + half*32;
    #pragma unroll
    for (int j = 0; j < 8; ++j) {
      float4 w = ld4(src + j*4);
      int k = half*32 + j*4;
      Bs[(k+0)*128+rw] = w.x; Bs[(k+1)*128+rw] = w.y;
      Bs[(k+2)*128+rw] = w.z; Bs[(k+3)*128+rw] = w.w;
    }
  }
  __syncthreads();
  const int mi = t >> 5, ni = t & 31;
  float acc[8][4];
  #pragma unroll
  for (int i = 0; i < 8; ++i)
    #pragma unroll
    for (int j = 0; j < 4; ++j) acc[i][j] = 0.f;
  #pragma unroll 8
  for (int k = 0; k < 64; ++k) {
    float a[8], bv[4];
    float4 a0 = *(const float4*)&As[k*64 + mi*8];
    float4 a1 = *(const float4*)&As[k*64 + mi*8 + 4];
    float4 b0 = *(const float4*)&Bs[k*128 + ni*4];
    a[0]=a0.x; a[1]=a0.y; a[2]=a0.z; a[3]=a0.w;
    a[4]=a1.x; a[5]=a1.y; a[6]=a1.z; a[7]=a1.w;
    bv[0]=b0.x; bv[1]=b0.y; bv[2]=b0.z; bv[3]=b0.w;
    #pragma unroll
    for (int im = 0; im < 8; ++im)
      #pragma unroll
      for (int in = 0; in < 4; ++in)
        acc[im][in] = fmaf(a[im], bv[in], acc[im][in]);
  }
  #pragma unroll
  for (int im = 0; im < 8; ++im) {
    float4 o; o.x=acc[im][0]; o.y=acc[im][1]; o.z=acc[im][2]; o.w=acc[im][3];
    *(float4*)&out[(size_t)(m0 + mi*8 + im)*1024 + n0 + ni*4] = o;
  }
}

// ---------------- launcher ----------------
extern "C" void kernel_launch(void* const* d_in, const int* in_sizes, int n_in,
                              void* d_out, int out_size, void* d_ws, size_t ws_size,
                              hipStream_t stream) {
  const float* x     = (const float*)d_in[0];
  const float* Wk    = (const float*)d_in[1];
  const float* Wv    = (const float*)d_in[2];
  const float* Wq    = (const float*)d_in[3];
  const float* fap   = (const float*)d_in[4];
  const float* sap   = (const float*)d_in[5];
  const float* nm_w1 = (const float*)d_in[6];
  const float* nm_b1 = (const float*)d_in[7];
  const float* nm_w2 = (const float*)d_in[8];
  const float* nm_b2 = (const float*)d_in[9];
  const float* ir_w1 = (const float*)d_in[10];
  const float* ir_b1 = (const float*)d_in[11];
  const float* ir_w2 = (const float*)d_in[12];
  const float* ir_b2 = (const float*)d_in[13];
  const float* pw    = (const float*)d_in[14];
  const float* Wo    = (const float*)d_in[15];
  const float* normw = (const float*)d_in[16];
  float* out = (float*)d_out;
  float* ws  = (float*)d_ws;

  // workspace layout (floats)
  const size_t oW    = 0;
  const size_t oY    = oW  + (size_t)320*1024;        // Wcat
  const size_t oK    = oY  + (size_t)MM*320;          // Y (reused below)
  const size_t oV    = oK  + (size_t)MM*64;
  const size_t oQ    = oV  + (size_t)MM*64;
  const size_t oNU   = oQ  + (size_t)MM*64;
  const size_t oPW   = oNU + (size_t)MM*64;
  const size_t oSCL  = oPW + (size_t)MM*3;            // SCL12: MM*12
  const size_t oCNS  = oSCL + (size_t)MM*12;
  // Y region reused after post_kernel (Y dead by then):
  const size_t oOBASE = oY;                    // MM*64
  const size_t oE     = oY + (size_t)MM*64;    // MM*64
  const size_t oVT    = oY + (size_t)2*MM*64;  // MM*64
  const size_t oOB    = oY + (size_t)3*MM*64;  // MM*64 (Y region = MM*320, fits)

  pack_w<<<1280, 256, 0, stream>>>(Wk, Wv, Wq, ir_w1, pw, ws + oW);
  gemm1<<<dim3(128, 5), 256, 0, stream>>>(x, ws + oW, ws + oY);
  post_kernel<<<1024, 256, 0, stream>>>(ws + oY, nm_w1, nm_b1, nm_w2, nm_b2,
                                        ir_b1, ir_w2, ir_b2, sap,
                                        ws + oK, ws + oV, ws + oQ, ws + oNU,
                                        ws + oPW, ws + oSCL);
  transpose_v<<<256, 256, 0, stream>>>(ws + oV, ws + oVT);
  crossdot_kernel<<<4096, 256, 0, stream>>>(ws + oK, ws + oQ, ws + oSCL);
  scan_kernel<<<512, 64, 0, stream>>>(ws + oK, ws + oQ, ws + oVT, ws + oSCL,
                                      fap, sap, ws + oOBASE, ws + oE);
  err_kernel<<<4096, 256, 0, stream>>>(ws + oE, ws + oCNS);
  nsout_kernel<<<8, 64, 0, stream>>>(ws + oCNS, ws + oNU, ws + oOBASE,
                                     ws + oPW, ws + oOB);
  out_gemm<<<dim3(8, 256), 256, 0, stream>>>(ws + oOB, Wo, normw, out);
}

// Round 9
// 786.504 us; speedup vs baseline: 1.1072x; 1.1072x over previous
//
#include <hip/hip_runtime.h>
#include <hip/hip_bf16.h>
#include <math.h>

// Problem constants (match reference)
#define BB 8
#define SS 2048
#define DD 1024
#define DS 64
#define MM (BB*SS)   // 16384

// ---------------- helpers ----------------

__device__ __forceinline__ float4 ld4(const float* p) { return *(const float4*)p; }

template<int CTRL>
__device__ __forceinline__ float dppadd(float x) {
  int v = __builtin_amdgcn_update_dpp(0, __float_as_int(x), CTRL, 0xf, 0xf, true);
  return x + __int_as_float(v);
}

// xor-16 / xor-32 butterfly-add stages via gfx950 permlane swaps (pure VALU).
__device__ __forceinline__ float xor16add(float x) {
#if defined(__has_builtin) && __has_builtin(__builtin_amdgcn_permlane16_swap)
  auto r = __builtin_amdgcn_permlane16_swap(__float_as_uint(x), __float_as_uint(x), false, false);
  return __uint_as_float(r[0]) + __uint_as_float(r[1]);
#else
  return x + __shfl_xor(x, 16, 64);
#endif
}
__device__ __forceinline__ float xor32add(float x) {
#if defined(__has_builtin) && __has_builtin(__builtin_amdgcn_permlane32_swap)
  auto r = __builtin_amdgcn_permlane32_swap(__float_as_uint(x), __float_as_uint(x), false, false);
  return __uint_as_float(r[0]) + __uint_as_float(r[1]);
#else
  return x + __shfl_xor(x, 32, 64);
#endif
}

// full 64-lane butterfly sum; result valid in all lanes
__device__ __forceinline__ float wsum(float x) {
  x = dppadd<0xB1>(x);   // quad_perm xor1
  x = dppadd<0x4E>(x);   // quad_perm xor2
  x = dppadd<0x141>(x);  // row_half_mirror (completes 8-group)
  x = dppadd<0x140>(x);  // row_mirror      (completes 16-group)
  x = xor16add(x);
  x = xor32add(x);
  return x;
}

__device__ __forceinline__ float gelu_exact(float x) {
  return 0.5f * x * (1.f + erff(x * 0.7071067811865476f));
}

// global -> LDS async staging (data lands at LDS base + lane*size)
__device__ __forceinline__ void gll16(const float* g, float* l) {
  __builtin_amdgcn_global_load_lds(
      (const __attribute__((address_space(1))) void*)g,
      (__attribute__((address_space(3))) void*)l, 16, 0, 0);
}
__device__ __forceinline__ void gll4(const float* g, float* l) {
  __builtin_amdgcn_global_load_lds(
      (const __attribute__((address_space(1))) void*)g,
      (__attribute__((address_space(3))) void*)l, 4, 0, 0);
}

// ---------------- k0: pack weights [Wk;Wv;Wq;ir_w1;pw;0-pad] -> Wcat[320][1024]
__global__ __launch_bounds__(256) void pack_w(
    const float* __restrict__ Wk, const float* __restrict__ Wv,
    const float* __restrict__ Wq, const float* __restrict__ ir_w1,
    const float* __restrict__ pw, float* __restrict__ Wcat) {
  int idx = blockIdx.x * 256 + threadIdx.x;   // 320*1024 total
  int r = idx >> 10, c = idx & 1023;
  float val = 0.f;
  if (r < 64)       val = Wk[r*1024 + c];
  else if (r < 128) val = Wv[(r-64)*1024 + c];
  else if (r < 192) val = Wq[(r-128)*1024 + c];
  else if (r < 256) val = ir_w1[(r-192)*1024 + c];
  else if (r < 259) val = pw[(r-256)*1024 + c];
  Wcat[idx] = val;
}

// ---------------- k1: Y[16384][320] = X[16384][1024] @ Wcat[320][1024]^T
__global__ __launch_bounds__(256) void gemm1(
    const float* __restrict__ X, const float* __restrict__ Wcat,
    float* __restrict__ Y) {
  __shared__ float As[32*128];   // [k][m]
  __shared__ float Bs[32*64];    // [k][n]
  const int t  = threadIdx.x;
  const int m0 = blockIdx.x * 128;
  const int n0 = blockIdx.y * 64;
  const int mi = t >> 4, ni = t & 15;
  const int rA = t >> 1, hA = t & 1;
  const int rB = t >> 2, qB = t & 3;
  float acc[8][4];
  #pragma unroll
  for (int i = 0; i < 8; ++i)
    #pragma unroll
    for (int j = 0; j < 4; ++j) acc[i][j] = 0.f;

  for (int k0 = 0; k0 < 1024; k0 += 32) {
    __syncthreads();
    {
      const float* src = X + (size_t)(m0 + rA)*1024 + k0 + hA*16;
      #pragma unroll
      for (int jj = 0; jj < 4; ++jj) {
        float4 xv = ld4(src + jj*4);
        int kk = hA*16 + jj*4;
        As[(kk+0)*128 + rA] = xv.x; As[(kk+1)*128 + rA] = xv.y;
        As[(kk+2)*128 + rA] = xv.z; As[(kk+3)*128 + rA] = xv.w;
      }
      const float* srcB = Wcat + (size_t)(n0 + rB)*1024 + k0 + qB*8;
      #pragma unroll
      for (int jj = 0; jj < 2; ++jj) {
        float4 bv = ld4(srcB + jj*4);
        int kb = qB*8 + jj*4;
        Bs[(kb+0)*64 + rB] = bv.x; Bs[(kb+1)*64 + rB] = bv.y;
        Bs[(kb+2)*64 + rB] = bv.z; Bs[(kb+3)*64 + rB] = bv.w;
      }
    }
    __syncthreads();
    #pragma unroll
    for (int kk = 0; kk < 32; ++kk) {
      float a[8], bv[4];
      float4 a0 = *(const float4*)&As[kk*128 + mi*8];
      float4 a1 = *(const float4*)&As[kk*128 + mi*8 + 4];
      float4 b0 = *(const float4*)&Bs[kk*64 + ni*4];
      a[0]=a0.x; a[1]=a0.y; a[2]=a0.z; a[3]=a0.w;
      a[4]=a1.x; a[5]=a1.y; a[6]=a1.z; a[7]=a1.w;
      bv[0]=b0.x; bv[1]=b0.y; bv[2]=b0.z; bv[3]=b0.w;
      #pragma unroll
      for (int im = 0; im < 8; ++im)
        #pragma unroll
        for (int in = 0; in < 4; ++in)
          acc[im][in] = fmaf(a[im], bv[in], acc[im][in]);
    }
  }
  #pragma unroll
  for (int im = 0; im < 8; ++im) {
    float4 o; o.x = acc[im][0]; o.y = acc[im][1]; o.z = acc[im][2]; o.w = acc[im][3];
    *(float4*)&Y[(size_t)(m0 + mi*8 + im)*320 + n0 + ni*4] = o;
  }
}

// ---------------- k2: per-token postprocess -> K,V,Q,NU,PW, SCL8[0..3]
__global__ __launch_bounds__(256) void post_kernel(
    const float* __restrict__ Y,
    const float* __restrict__ nm_w1, const float* __restrict__ nm_b1,
    const float* __restrict__ nm_w2, const float* __restrict__ nm_b2,
    const float* __restrict__ ir_b1, const float* __restrict__ ir_w2,
    const float* __restrict__ ir_b2, const float* __restrict__ sap,
    float* __restrict__ K, float* __restrict__ V, float* __restrict__ Q,
    float* __restrict__ NU, float* __restrict__ PW,
    float* __restrict__ SCL8) {
  __shared__ float w1s[128*65];
  __shared__ float w2s[64*129];
  __shared__ float vbuf[4][64];
  __shared__ float h1buf[4][128];
  const int tid = threadIdx.x, wid = tid >> 6, l = tid & 63;
  for (int i = tid; i < 128*64; i += 256) w1s[(i>>6)*65 + (i&63)]  = nm_w1[i];
  for (int i = tid; i < 64*128; i += 256) w2s[(i>>7)*129 + (i&127)] = nm_w2[i];
  __syncthreads();
  const float sa   = *sap;
  const float b1a  = nm_b1[l], b1b = nm_b1[64+l], b2l = nm_b2[l];
  const float irb1 = ir_b1[l], irw2 = ir_w2[l],  irb2 = ir_b2[0];
  for (int r = 0; r < 4; ++r) {
    const int tok = blockIdx.x*16 + r*4 + wid;
    const float* yr = Y + (size_t)tok*320;
    float kr = yr[l], vr = yr[64+l], qr = yr[128+l], hr = yr[192+l];
    float rk = 1.f / fmaxf(sqrtf(wsum(kr*kr)), 1e-12f);
    float rq = 1.f / fmaxf(sqrtf(wsum(qr*qr)), 1e-12f);
    float kn = kr*rk, qn = qr*rq;
    float qk = wsum(kn*qn);
    float g  = gelu_exact(hr + irb1);
    float logit = wsum(g*irw2) + irb2;
    float imp = 1.f/(1.f+expf(-logit));
    float bs  = (imp > 0.5f) ? (1.f - sa) : 0.f;   // (1-slow_alpha)*u_slow
    K[(size_t)tok*64+l] = kn; V[(size_t)tok*64+l] = vr; Q[(size_t)tok*64+l] = qn;
    vbuf[wid][l] = vr;
    __syncthreads();
    float h1a = b1a, h1b = b1b;
    #pragma unroll 8
    for (int c = 0; c < 64; ++c) {
      float vv = vbuf[wid][c];
      h1a = fmaf(w1s[l*65 + c], vv, h1a);
      h1b = fmaf(w1s[(64+l)*65 + c], vv, h1b);
    }
    h1buf[wid][l]    = gelu_exact(h1a);
    h1buf[wid][64+l] = gelu_exact(h1b);
    __syncthreads();
    float nu = b2l;
    #pragma unroll 8
    for (int j = 0; j < 128; ++j) nu = fmaf(w2s[l*129 + j], h1buf[wid][j], nu);
    NU[(size_t)tok*64+l] = nu;
    float p0 = yr[256], p1 = yr[257], p2 = yr[258];
    float mx = fmaxf(p0, fmaxf(p1, p2));
    float e0 = expf(p0-mx), e1 = expf(p1-mx), e2 = expf(p2-mx);
    float inv = 1.f/(e0+e1+e2);
    if (l == 0) {
      PW[(size_t)tok*3]   = e0*inv;
      float4 s; s.x = qk; s.y = bs; s.z = e0*inv; s.w = e1*inv;
      *(float4*)&SCL8[(size_t)tok*8] = s;
    }
    else if (l == 1)   PW[(size_t)tok*3+1] = e1*inv;
    else if (l == 2)   PW[(size_t)tok*3+2] = e2*inv;
    __syncthreads();
  }
}

// ---------------- k2b: V[b][t][v] -> VT[b][v][t] (64x64 LDS tiles)
__global__ __launch_bounds__(256) void transpose_v(
    const float* __restrict__ V, float* __restrict__ VT) {
  __shared__ float tile[64][65];
  const int b  = blockIdx.x >> 5;
  const int t0 = (blockIdx.x & 31) * 64;
  const int tid = threadIdx.x;
  const int rr = tid >> 6, cc = tid & 63;
  #pragma unroll
  for (int r4 = 0; r4 < 64; r4 += 4) {
    int t = t0 + r4 + rr;
    tile[r4 + rr][cc] = V[((size_t)b*SS + t)*64 + cc];
  }
  __syncthreads();
  #pragma unroll
  for (int r4 = 0; r4 < 64; r4 += 4) {
    int vv = r4 + rr;
    VT[((size_t)b*64 + vv)*SS + t0 + cc] = tile[cc][vv];
  }
}

// ---------------- k2c: cross-token dots -> SCL8[4..7] = (kk1,qk1,kk2,qk2)
__global__ __launch_bounds__(256) void crossdot_kernel(
    const float* __restrict__ K, const float* __restrict__ Q,
    float* __restrict__ SCL8) {
  const int tok = blockIdx.x*4 + (threadIdx.x >> 6);
  const int l = threadIdx.x & 63;
  const int tloc = tok & (SS-1);
  const float kt = K[(size_t)tok*64 + l];
  const float qt = Q[(size_t)tok*64 + l];
  const float kp1 = (tloc >= 1) ? K[(size_t)(tok-1)*64 + l] : 0.f;
  const float kp2 = (tloc >= 2) ? K[(size_t)(tok-2)*64 + l] : 0.f;
  float kk1 = wsum(kt*kp1);
  float qk1 = wsum(qt*kp1);
  float kk2 = wsum(kt*kp2);
  float qk2 = wsum(qt*kp2);
  if (l == 0) {
    float4 o; o.x = kk1; o.y = qk1; o.z = kk2; o.w = qk2;
    *(float4*)&SCL8[(size_t)tok*8 + 4] = o;
  }
}

// ---------------- k3: sequential scan, column-parallel, D=2 WY-deferred,
// 4-step register groups pinned by sched_barrier.
// One wave per (b, v). Lane l holds fH[l][v], sH[l][v].
//   pf_t = fa^2*(k_t.fH_{t-3}) + gf_{t-1}*kk1_t + fa*gf_{t-2}*kk2_t
// dff_t = k_t.fH_{t-3} is launched at step t-2 (pre-update fH of that step).
// All per-step operands are in registers loaded one 4-step group earlier;
// sched_barrier(0) fences each {issue | body} so the distance can't collapse.
#define CH 64
__global__ __launch_bounds__(64) void scan_kernel(
    const float* __restrict__ K, const float* __restrict__ Q,
    const float* __restrict__ VT, const float* __restrict__ SCL8,
    const float* __restrict__ fap, const float* __restrict__ sap,
    float* __restrict__ OBASE, float* __restrict__ E) {
  __shared__ float lK[2][CH*64];   // 32 KB
  __shared__ float lQ[2][CH*64];   // 32 KB
  __shared__ float lV[2][CH];      // 512 B
  __shared__ float lS[2][CH*8];    // 4 KB
  const int b = blockIdx.x >> 6;
  const int v = blockIdx.x & 63;
  const int l = threadIdx.x;
  const float fa = *fap, sal = *sap, omfa = 1.f - fa;
  const float fa2 = fa*fa, sa2 = sal*sal;
  const size_t base = (size_t)b * SS * 64;
  const float* gK = K + base + l*4;
  const float* gQ = Q + base + l*4;
  const float* gV = VT + ((size_t)b*64 + v)*SS + l;
  const float* gS = SCL8 + (size_t)b*SS*8 + l*4;
  float* stp = ((l == 32) ? E : OBASE) + base + v;

  float fH = 0.f, sH = 0.f;
  float dff[4] = {0.f,0.f,0.f,0.f}, dqf[4] = {0.f,0.f,0.f,0.f};
  float dss[4] = {0.f,0.f,0.f,0.f}, dqs[4] = {0.f,0.f,0.f,0.f};
  float gf1 = 0.f, gf2 = 0.f, gs1 = 0.f, gs2 = 0.f;
  float  kR[2][4], qR[2][4], vR[2][4];
  float4 aR[2][4], bR[2][4];

#define STAGE(buf, c) {                                              \
    const float* kc_ = gK + (size_t)(c)*CH*64;                       \
    const float* qc_ = gQ + (size_t)(c)*CH*64;                       \
    _Pragma("unroll")                                                \
    for (int j = 0; j < 16; ++j) {                                   \
      gll16(kc_ + j*256, &lK[buf][j*256]);                           \
      gll16(qc_ + j*256, &lQ[buf][j*256]);                           \
    }                                                                \
    gll4(gV + (size_t)(c)*CH, &lV[buf][0]);                          \
    gll16(gS + (size_t)(c)*CH*8,       &lS[buf][0]);                 \
    gll16(gS + (size_t)(c)*CH*8 + 256, &lS[buf][256]); }

#define VMDRAIN { asm volatile("s_waitcnt vmcnt(0)" ::: "memory");   \
                  __builtin_amdgcn_sched_barrier(0); }

  // load token TT (chunk-local, may be >= CH -> next buffer) into set S slot I
#define LOADTOK(S, I, TT) {                                          \
    if ((TT) < CH) {                                                 \
      kR[S][I] = lK[cur][(TT)*64 + l];                               \
      qR[S][I] = lQ[cur][(TT)*64 + l];                               \
      vR[S][I] = lV[cur][(TT)];                                      \
      aR[S][I] = *(const float4*)&lS[cur][(TT)*8];                   \
      bR[S][I] = *(const float4*)&lS[cur][(TT)*8 + 4];               \
    } else {                                                         \
      kR[S][I] = lK[nxt][((TT)-CH)*64 + l];                          \
      qR[S][I] = lQ[nxt][((TT)-CH)*64 + l];                          \
      vR[S][I] = lV[nxt][(TT)-CH];                                   \
      aR[S][I] = *(const float4*)&lS[nxt][((TT)-CH)*8];              \
      bR[S][I] = *(const float4*)&lS[nxt][((TT)-CH)*8 + 4];          \
    } }

  // Step T (chunk-local literal 0..63).
#define STEPX(T) {                                                   \
    const float kf = kR[(((T)+2)>>2)&1][((T)+2)&3];                  \
    const float qf = qR[(((T)+2)>>2)&1][((T)+2)&3];                  \
    const float ndff = wsum(kf*fH), ndqf = wsum(qf*fH);              \
    const float ndss = wsum(kf*sH), ndqs = wsum(qf*sH);              \
    const float  kc = kR[((T)>>2)&1][(T)&3];                         \
    const float  vc = vR[((T)>>2)&1][(T)&3];                         \
    const float4 A  = aR[((T)>>2)&1][(T)&3];                         \
    const float4 Bv = bR[((T)>>2)&1][(T)&3];                         \
    const float agf = fa*gf2, ags = sal*gs2;                         \
    const float pf  = fmaf(fa2, dff[(T)&3], fmaf(gf1, Bv.x, agf*Bv.z)); \
    const float pq  = fmaf(fa2, dqf[(T)&3], fmaf(gf1, Bv.y, agf*Bv.w)); \
    const float ps  = fmaf(sa2, dss[(T)&3], fmaf(gs1, Bv.x, ags*Bv.z)); \
    const float pqs = fmaf(sa2, dqs[(T)&3], fmaf(gs1, Bv.y, ags*Bv.w)); \
    const float gf = omfa*(vc - pf);                                 \
    const float gs = A.y*(vc - ps);                                  \
    const float qfn = fmaf(gf, A.x, fa*pq);                          \
    const float qsn = fmaf(gs, A.x, sal*pqs);                        \
    const float pd = vc - 0.5f*(pq + pqs);                           \
    val[(T)&3] = (l == 32) ? pd*pd : fmaf(A.z, qfn, A.w*qsn);        \
    fH = fmaf(gf, kc, fa*fH);                                        \
    sH = fmaf(gs, kc, sal*sH);                                       \
    gf2 = gf1; gf1 = gf; gs2 = gs1; gs1 = gs;                        \
    dff[((T)+2)&3] = ndff; dqf[((T)+2)&3] = ndqf;                    \
    dss[((T)+2)&3] = ndss; dqs[((T)+2)&3] = ndqs; }

#define GROUP(G) {                                                   \
    LOADTOK((((G)+1)&1), 0, 4*((G)+1)+0)                             \
    LOADTOK((((G)+1)&1), 1, 4*((G)+1)+1)                             \
    LOADTOK((((G)+1)&1), 2, 4*((G)+1)+2)                             \
    LOADTOK((((G)+1)&1), 3, 4*((G)+1)+3)                             \
    __builtin_amdgcn_sched_barrier(0);                               \
    float val[4];                                                    \
    STEPX(4*(G)+0) STEPX(4*(G)+1) STEPX(4*(G)+2) STEPX(4*(G)+3)      \
    if (l == 0 || l == 32) {                                         \
      stp[(size_t)(cbase + 4*(G) + 0)*64] = val[0];                  \
      stp[(size_t)(cbase + 4*(G) + 1)*64] = val[1];                  \
      stp[(size_t)(cbase + 4*(G) + 2)*64] = val[2];                  \
      stp[(size_t)(cbase + 4*(G) + 3)*64] = val[3];                  \
    }                                                                \
    __builtin_amdgcn_sched_barrier(0);                               \
    if ((G) == 14) VMDRAIN }

  STAGE(0, 0)
  VMDRAIN
  int cur = 0, nxt = 1;
  // prime set 0 with chunk-0 tokens 0..3
  #pragma unroll
  for (int i = 0; i < 4; ++i) {
    kR[0][i] = lK[0][i*64 + l];
    qR[0][i] = lQ[0][i*64 + l];
    vR[0][i] = lV[0][i];
    aR[0][i] = *(const float4*)&lS[0][i*8];
    bR[0][i] = *(const float4*)&lS[0][i*8 + 4];
  }
  for (int c = 0; c < 32; ++c) {
    nxt = cur ^ 1;
    if (c + 1 < 32) STAGE(nxt, c + 1)
    const int cbase = c*CH;
    GROUP(0)  GROUP(1)  GROUP(2)  GROUP(3)
    GROUP(4)  GROUP(5)  GROUP(6)  GROUP(7)
    GROUP(8)  GROUP(9)  GROUP(10) GROUP(11)
    GROUP(12) GROUP(13) GROUP(14) GROUP(15)
    cur = nxt;
  }
#undef STAGE
#undef VMDRAIN
#undef LOADTOK
#undef STEPX
#undef GROUP
}

// ---------------- k4: err reduce -> ns-gate coefficient c = 0.1*u_neu
__global__ __launch_bounds__(256) void err_kernel(
    const float* __restrict__ E, float* __restrict__ CNS) {
  int row = blockIdx.x*4 + (threadIdx.x >> 6);
  int l = threadIdx.x & 63;
  float s = wsum(E[(size_t)row*64 + l]);
  if (l == 0) {
    float z = s / (1.0f + 1e-6f);          // TEMP + 1e-6
    float sg = 1.f/(1.f+expf(-z));
    CNS[row] = (sg > 0.7f) ? 0.1f : 0.f;
  }
}

// ---------------- k5: ns scan + o assembly, software-pipelined
#define BW 16
__device__ __forceinline__ void loadw(int b, int t0, int v,
    const float* __restrict__ CNS, const float* __restrict__ NU,
    const float* __restrict__ OBASE, const float* __restrict__ PW,
    float* c, float* nu, float* ob, float* p2) {
  #pragma unroll
  for (int i = 0; i < BW; ++i) {
    size_t bt = (size_t)b*SS + (t0 + i);
    c[i]  = CNS[bt];
    nu[i] = NU[bt*64 + v];
    ob[i] = OBASE[bt*64 + v];
    p2[i] = PW[bt*3 + 2];
  }
}
__device__ __forceinline__ float procw(int b, int t0, int v, float ns,
    const float* c, const float* nu, const float* ob, const float* p2,
    float* __restrict__ OB) {
  #pragma unroll
  for (int i = 0; i < BW; ++i) {
    float cn = c[i]*nu[i];
    float a  = 1.f - c[i];
    ns = fmaf(a, ns, cn);                 // ns = (1-c)*ns + c*nu
    float o = fmaf(p2[i], ns, ob[i]);
    OB[((size_t)b*SS + (t0+i))*64 + v] = o;
  }
  return ns;
}
__global__ __launch_bounds__(64) void nsout_kernel(
    const float* __restrict__ CNS, const float* __restrict__ NU,
    const float* __restrict__ OBASE, const float* __restrict__ PW,
    float* __restrict__ OB) {
  const int b = blockIdx.x, v = threadIdx.x;
  float cA[BW],nA[BW],oA[BW],pA[BW], cB[BW],nB[BW],oB[BW],pB[BW];
  loadw(b, 0, v, CNS, NU, OBASE, PW, cA, nA, oA, pA);
  float ns = 0.f;
  for (int t0 = 0; t0 < SS; t0 += 2*BW) {
    int tB = t0 + BW;
    loadw(b, tB, v, CNS, NU, OBASE, PW, cB, nB, oB, pB);
    ns = procw(b, t0, v, ns, cA, nA, oA, pA, OB);
    int tA2 = t0 + 2*BW; if (tA2 > SS - BW) tA2 = SS - BW;
    loadw(b, tA2, v, CNS, NU, OBASE, PW, cA, nA, oA, pA);
    ns = procw(b, tB, v, ns, cB, nB, oB, pB, OB);
  }
}

// ---------------- k6: fused RMSNorm + out = normed @ Wo^T
__global__ __launch_bounds__(256) void out_gemm(
    const float* __restrict__ OB, const float* __restrict__ Wo,
    const float* __restrict__ normw, float* __restrict__ out) {
  __shared__ float As[64*64];    // [k][m]
  __shared__ float Bs[64*128];   // [k][n]
  const int t  = threadIdx.x;
  const int m0 = blockIdx.y * 64;
  const int n0 = blockIdx.x * 128;
  {
    int r = t >> 2, q4 = t & 3;
    const float* src = OB + (size_t)(m0 + r)*64 + q4*16;
    float4 x0 = ld4(src), x1 = ld4(src+4), x2 = ld4(src+8), x3 = ld4(src+12);
    float ss = x0.x*x0.x+x0.y*x0.y+x0.z*x0.z+x0.w*x0.w
             + x1.x*x1.x+x1.y*x1.y+x1.z*x1.z+x1.w*x1.w
             + x2.x*x2.x+x2.y*x2.y+x2.z*x2.z+x2.w*x2.w
             + x3.x*x3.x+x3.y*x3.y+x3.z*x3.z+x3.w*x3.w;
    ss += __shfl_xor(ss, 1, 64);
    ss += __shfl_xor(ss, 2, 64);
    float rms = rsqrtf(ss * (1.f/64.f) + 1e-6f);
    const float* nw = normw + q4*16;
    float4 w0 = ld4(nw), w1 = ld4(nw+4), w2 = ld4(nw+8), w3 = ld4(nw+12);
    int kbase = q4*16;
    As[(kbase+ 0)*64+r]=x0.x*rms*w0.x; As[(kbase+ 1)*64+r]=x0.y*rms*w0.y;
    As[(kbase+ 2)*64+r]=x0.z*rms*w0.z; As[(kbase+ 3)*64+r]=x0.w*rms*w0.w;
    As[(kbase+ 4)*64+r]=x1.x*rms*w1.x; As[(kbase+ 5)*64+r]=x1.y*rms*w1.y;
    As[(kbase+ 6)*64+r]=x1.z*rms*w1.z; As[(kbase+ 7)*64+r]=x1.w*rms*w1.w;
    As[(kbase+ 8)*64+r]=x2.x*rms*w2.x; As[(kbase+ 9)*64+r]=x2.y*rms*w2.y;
    As[(kbase+10)*64+r]=x2.z*rms*w2.z; As[(kbase+11)*64+r]=x2.w*rms*w2.w;
    As[(kbase+12)*64+r]=x3.x*rms*w3.x; As[(kbase+13)*64+r]=x3.y*rms*w3.y;
    As[(kbase+14)*64+r]=x3.z*rms*w3.z; As[(kbase+15)*64+r]=x3.w*rms*w3.w;
  }
  {
    int rw = t >> 1, half = t & 1;
    const float* src = Wo + (size_t)(n0 + rw)*64 + half*32;
    #pragma unroll
    for (int j = 0; j < 8; ++j) {
      float4 w = ld4(src + j*4);
      int k = half*32 + j*4;
      Bs[(k+0)*128+rw] = w.x; Bs[(k+1)*128+rw] = w.y;
      Bs[(k+2)*128+rw] = w.z; Bs[(k+3)*128+rw] = w.w;
    }
  }
  __syncthreads();
  const int mi = t >> 5, ni = t & 31;
  float acc[8][4];
  #pragma unroll
  for (int i = 0; i < 8; ++i)
    #pragma unroll
    for (int j = 0; j < 4; ++j) acc[i][j] = 0.f;
  #pragma unroll 8
  for (int k = 0; k < 64; ++k) {
    float a[8], bv[4];
    float4 a0 = *(const float4*)&As[k*64 + mi*8];
    float4 a1 = *(const float4*)&As[k*64 + mi*8 + 4];
    float4 b0 = *(const float4*)&Bs[k*128 + ni*4];
    a[0]=a0.x; a[1]=a0.y; a[2]=a0.z; a[3]=a0.w;
    a[4]=a1.x; a[5]=a1.y; a[6]=a1.z; a[7]=a1.w;
    bv[0]=b0.x; bv[1]=b0.y; bv[2]=b0.z; bv[3]=b0.w;
    #pragma unroll
    for (int im = 0; im < 8; ++im)
      #pragma unroll
      for (int in = 0; in < 4; ++in)
        acc[im][in] = fmaf(a[im], bv[in], acc[im][in]);
  }
  #pragma unroll
  for (int im = 0; im < 8; ++im) {
    float4 o; o.x=acc[im][0]; o.y=acc[im][1]; o.z=acc[im][2]; o.w=acc[im][3];
    *(float4*)&out[(size_t)(m0 + mi*8 + im)*1024 + n0 + ni*4] = o;
  }
}

// ---------------- launcher ----------------
extern "C" void kernel_launch(void* const* d_in, const int* in_sizes, int n_in,
                              void* d_out, int out_size, void* d_ws, size_t ws_size,
                              hipStream_t stream) {
  const float* x     = (const float*)d_in[0];
  const float* Wk    = (const float*)d_in[1];
  const float* Wv    = (const float*)d_in[2];
  const float* Wq    = (const float*)d_in[3];
  const float* fap   = (const float*)d_in[4];
  const float* sap   = (const float*)d_in[5];
  const float* nm_w1 = (const float*)d_in[6];
  const float* nm_b1 = (const float*)d_in[7];
  const float* nm_w2 = (const float*)d_in[8];
  const float* nm_b2 = (const float*)d_in[9];
  const float* ir_w1 = (const float*)d_in[10];
  const float* ir_b1 = (const float*)d_in[11];
  const float* ir_w2 = (const float*)d_in[12];
  const float* ir_b2 = (const float*)d_in[13];
  const float* pw    = (const float*)d_in[14];
  const float* Wo    = (const float*)d_in[15];
  const float* normw = (const float*)d_in[16];
  float* out = (float*)d_out;
  float* ws  = (float*)d_ws;

  // workspace layout (floats)
  const size_t oW    = 0;
  const size_t oY    = oW  + (size_t)320*1024;        // Wcat
  const size_t oK    = oY  + (size_t)MM*320;          // Y (reused below)
  const size_t oV    = oK  + (size_t)MM*64;
  const size_t oQ    = oV  + (size_t)MM*64;
  const size_t oNU   = oQ  + (size_t)MM*64;
  const size_t oPW   = oNU + (size_t)MM*64;
  const size_t oSCL  = oPW + (size_t)MM*3;            // SCL8: MM*8
  const size_t oCNS  = oSCL + (size_t)MM*8;
  // Y region reused after post_kernel (Y dead by then):
  const size_t oOBASE = oY;                    // MM*64
  const size_t oE     = oY + (size_t)MM*64;    // MM*64
  const size_t oVT    = oY + (size_t)2*MM*64;  // MM*64
  const size_t oOB    = oY + (size_t)3*MM*64;  // MM*64 (Y region = MM*320, fits)

  pack_w<<<1280, 256, 0, stream>>>(Wk, Wv, Wq, ir_w1, pw, ws + oW);
  gemm1<<<dim3(128, 5), 256, 0, stream>>>(x, ws + oW, ws + oY);
  post_kernel<<<1024, 256, 0, stream>>>(ws + oY, nm_w1, nm_b1, nm_w2, nm_b2,
                                        ir_b1, ir_w2, ir_b2, sap,
                                        ws + oK, ws + oV, ws + oQ, ws + oNU,
                                        ws + oPW, ws + oSCL);
  transpose_v<<<256, 256, 0, stream>>>(ws + oV, ws + oVT);
  crossdot_kernel<<<4096, 256, 0, stream>>>(ws + oK, ws + oQ, ws + oSCL);
  scan_kernel<<<512, 64, 0, stream>>>(ws + oK, ws + oQ, ws + oVT, ws + oSCL,
                                      fap, sap, ws + oOBASE, ws + oE);
  err_kernel<<<4096, 256, 0, stream>>>(ws + oE, ws + oCNS);
  nsout_kernel<<<8, 64, 0, stream>>>(ws + oCNS, ws + oNU, ws + oOBASE,
                                     ws + oPW, ws + oOB);
  out_gemm<<<dim3(8, 256), 256, 0, stream>>>(ws + oOB, Wo, normw, out);
}

// Round 10
// 786.409 us; speedup vs baseline: 1.1073x; 1.0001x over previous
//
#include <hip/hip_runtime.h>
#include <hip/hip_bf16.h>
#include <math.h>

// Problem constants (match reference)
#define BB 8
#define SS 2048
#define DD 1024
#define DS 64
#define MM (BB*SS)   // 16384

// ---------------- helpers ----------------

__device__ __forceinline__ float4 ld4(const float* p) { return *(const float4*)p; }

template<int CTRL>
__device__ __forceinline__ float dppadd(float x) {
  int v = __builtin_amdgcn_update_dpp(0, __float_as_int(x), CTRL, 0xf, 0xf, true);
  return x + __int_as_float(v);
}

// xor-16 / xor-32 butterfly-add stages via gfx950 permlane swaps (pure VALU).
__device__ __forceinline__ float xor16add(float x) {
#if defined(__has_builtin) && __has_builtin(__builtin_amdgcn_permlane16_swap)
  auto r = __builtin_amdgcn_permlane16_swap(__float_as_uint(x), __float_as_uint(x), false, false);
  return __uint_as_float(r[0]) + __uint_as_float(r[1]);
#else
  return x + __shfl_xor(x, 16, 64);
#endif
}
__device__ __forceinline__ float xor32add(float x) {
#if defined(__has_builtin) && __has_builtin(__builtin_amdgcn_permlane32_swap)
  auto r = __builtin_amdgcn_permlane32_swap(__float_as_uint(x), __float_as_uint(x), false, false);
  return __uint_as_float(r[0]) + __uint_as_float(r[1]);
#else
  return x + __shfl_xor(x, 32, 64);
#endif
}

// full 64-lane butterfly sum; result valid in all lanes
__device__ __forceinline__ float wsum(float x) {
  x = dppadd<0xB1>(x);   // quad_perm xor1
  x = dppadd<0x4E>(x);   // quad_perm xor2
  x = dppadd<0x141>(x);  // row_half_mirror (completes 8-group)
  x = dppadd<0x140>(x);  // row_mirror      (completes 16-group)
  x = xor16add(x);
  x = xor32add(x);
  return x;
}

__device__ __forceinline__ float gelu_exact(float x) {
  return 0.5f * x * (1.f + erff(x * 0.7071067811865476f));
}

// global -> LDS async staging (data lands at LDS base + lane*size)
__device__ __forceinline__ void gll16(const float* g, float* l) {
  __builtin_amdgcn_global_load_lds(
      (const __attribute__((address_space(1))) void*)g,
      (__attribute__((address_space(3))) void*)l, 16, 0, 0);
}
__device__ __forceinline__ void gll4(const float* g, float* l) {
  __builtin_amdgcn_global_load_lds(
      (const __attribute__((address_space(1))) void*)g,
      (__attribute__((address_space(3))) void*)l, 4, 0, 0);
}

// ---------------- k0: pack weights [Wk;Wv;Wq;ir_w1;pw;0-pad] -> Wcat[320][1024]
__global__ __launch_bounds__(256) void pack_w(
    const float* __restrict__ Wk, const float* __restrict__ Wv,
    const float* __restrict__ Wq, const float* __restrict__ ir_w1,
    const float* __restrict__ pw, float* __restrict__ Wcat) {
  int idx = blockIdx.x * 256 + threadIdx.x;   // 320*1024 total
  int r = idx >> 10, c = idx & 1023;
  float val = 0.f;
  if (r < 64)       val = Wk[r*1024 + c];
  else if (r < 128) val = Wv[(r-64)*1024 + c];
  else if (r < 192) val = Wq[(r-128)*1024 + c];
  else if (r < 256) val = ir_w1[(r-192)*1024 + c];
  else if (r < 259) val = pw[(r-256)*1024 + c];
  Wcat[idx] = val;
}

// ---------------- k1: Y[16384][320] = X[16384][1024] @ Wcat[320][1024]^T
__global__ __launch_bounds__(256) void gemm1(
    const float* __restrict__ X, const float* __restrict__ Wcat,
    float* __restrict__ Y) {
  __shared__ float As[32*128];   // [k][m]
  __shared__ float Bs[32*64];    // [k][n]
  const int t  = threadIdx.x;
  const int m0 = blockIdx.x * 128;
  const int n0 = blockIdx.y * 64;
  const int mi = t >> 4, ni = t & 15;
  const int rA = t >> 1, hA = t & 1;
  const int rB = t >> 2, qB = t & 3;
  float acc[8][4];
  #pragma unroll
  for (int i = 0; i < 8; ++i)
    #pragma unroll
    for (int j = 0; j < 4; ++j) acc[i][j] = 0.f;

  for (int k0 = 0; k0 < 1024; k0 += 32) {
    __syncthreads();
    {
      const float* src = X + (size_t)(m0 + rA)*1024 + k0 + hA*16;
      #pragma unroll
      for (int jj = 0; jj < 4; ++jj) {
        float4 xv = ld4(src + jj*4);
        int kk = hA*16 + jj*4;
        As[(kk+0)*128 + rA] = xv.x; As[(kk+1)*128 + rA] = xv.y;
        As[(kk+2)*128 + rA] = xv.z; As[(kk+3)*128 + rA] = xv.w;
      }
      const float* srcB = Wcat + (size_t)(n0 + rB)*1024 + k0 + qB*8;
      #pragma unroll
      for (int jj = 0; jj < 2; ++jj) {
        float4 bv = ld4(srcB + jj*4);
        int kb = qB*8 + jj*4;
        Bs[(kb+0)*64 + rB] = bv.x; Bs[(kb+1)*64 + rB] = bv.y;
        Bs[(kb+2)*64 + rB] = bv.z; Bs[(kb+3)*64 + rB] = bv.w;
      }
    }
    __syncthreads();
    #pragma unroll
    for (int kk = 0; kk < 32; ++kk) {
      float a[8], bv[4];
      float4 a0 = *(const float4*)&As[kk*128 + mi*8];
      float4 a1 = *(const float4*)&As[kk*128 + mi*8 + 4];
      float4 b0 = *(const float4*)&Bs[kk*64 + ni*4];
      a[0]=a0.x; a[1]=a0.y; a[2]=a0.z; a[3]=a0.w;
      a[4]=a1.x; a[5]=a1.y; a[6]=a1.z; a[7]=a1.w;
      bv[0]=b0.x; bv[1]=b0.y; bv[2]=b0.z; bv[3]=b0.w;
      #pragma unroll
      for (int im = 0; im < 8; ++im)
        #pragma unroll
        for (int in = 0; in < 4; ++in)
          acc[im][in] = fmaf(a[im], bv[in], acc[im][in]);
    }
  }
  #pragma unroll
  for (int im = 0; im < 8; ++im) {
    float4 o; o.x = acc[im][0]; o.y = acc[im][1]; o.z = acc[im][2]; o.w = acc[im][3];
    *(float4*)&Y[(size_t)(m0 + mi*8 + im)*320 + n0 + ni*4] = o;
  }
}

// ---------------- k2: per-token postprocess -> K,V,Q,NU,PW, SCL8[0..3]
__global__ __launch_bounds__(256) void post_kernel(
    const float* __restrict__ Y,
    const float* __restrict__ nm_w1, const float* __restrict__ nm_b1,
    const float* __restrict__ nm_w2, const float* __restrict__ nm_b2,
    const float* __restrict__ ir_b1, const float* __restrict__ ir_w2,
    const float* __restrict__ ir_b2, const float* __restrict__ sap,
    float* __restrict__ K, float* __restrict__ V, float* __restrict__ Q,
    float* __restrict__ NU, float* __restrict__ PW,
    float* __restrict__ SCL8) {
  __shared__ float w1s[128*65];
  __shared__ float w2s[64*129];
  __shared__ float vbuf[4][64];
  __shared__ float h1buf[4][128];
  const int tid = threadIdx.x, wid = tid >> 6, l = tid & 63;
  for (int i = tid; i < 128*64; i += 256) w1s[(i>>6)*65 + (i&63)]  = nm_w1[i];
  for (int i = tid; i < 64*128; i += 256) w2s[(i>>7)*129 + (i&127)] = nm_w2[i];
  __syncthreads();
  const float sa   = *sap;
  const float b1a  = nm_b1[l], b1b = nm_b1[64+l], b2l = nm_b2[l];
  const float irb1 = ir_b1[l], irw2 = ir_w2[l],  irb2 = ir_b2[0];
  for (int r = 0; r < 4; ++r) {
    const int tok = blockIdx.x*16 + r*4 + wid;
    const float* yr = Y + (size_t)tok*320;
    float kr = yr[l], vr = yr[64+l], qr = yr[128+l], hr = yr[192+l];
    float rk = 1.f / fmaxf(sqrtf(wsum(kr*kr)), 1e-12f);
    float rq = 1.f / fmaxf(sqrtf(wsum(qr*qr)), 1e-12f);
    float kn = kr*rk, qn = qr*rq;
    float qk = wsum(kn*qn);
    float g  = gelu_exact(hr + irb1);
    float logit = wsum(g*irw2) + irb2;
    float imp = 1.f/(1.f+expf(-logit));
    float bs  = (imp > 0.5f) ? (1.f - sa) : 0.f;   // (1-slow_alpha)*u_slow
    K[(size_t)tok*64+l] = kn; V[(size_t)tok*64+l] = vr; Q[(size_t)tok*64+l] = qn;
    vbuf[wid][l] = vr;
    __syncthreads();
    float h1a = b1a, h1b = b1b;
    #pragma unroll 8
    for (int c = 0; c < 64; ++c) {
      float vv = vbuf[wid][c];
      h1a = fmaf(w1s[l*65 + c], vv, h1a);
      h1b = fmaf(w1s[(64+l)*65 + c], vv, h1b);
    }
    h1buf[wid][l]    = gelu_exact(h1a);
    h1buf[wid][64+l] = gelu_exact(h1b);
    __syncthreads();
    float nu = b2l;
    #pragma unroll 8
    for (int j = 0; j < 128; ++j) nu = fmaf(w2s[l*129 + j], h1buf[wid][j], nu);
    NU[(size_t)tok*64+l] = nu;
    float p0 = yr[256], p1 = yr[257], p2 = yr[258];
    float mx = fmaxf(p0, fmaxf(p1, p2));
    float e0 = expf(p0-mx), e1 = expf(p1-mx), e2 = expf(p2-mx);
    float inv = 1.f/(e0+e1+e2);
    if (l == 0) {
      PW[(size_t)tok*3]   = e0*inv;
      float4 s; s.x = qk; s.y = bs; s.z = e0*inv; s.w = e1*inv;
      *(float4*)&SCL8[(size_t)tok*8] = s;
    }
    else if (l == 1)   PW[(size_t)tok*3+1] = e1*inv;
    else if (l == 2)   PW[(size_t)tok*3+2] = e2*inv;
    __syncthreads();
  }
}

// ---------------- k2b: V[b][t][v] -> VT[b][v][t] (64x64 LDS tiles)
__global__ __launch_bounds__(256) void transpose_v(
    const float* __restrict__ V, float* __restrict__ VT) {
  __shared__ float tile[64][65];
  const int b  = blockIdx.x >> 5;
  const int t0 = (blockIdx.x & 31) * 64;
  const int tid = threadIdx.x;
  const int rr = tid >> 6, cc = tid & 63;
  #pragma unroll
  for (int r4 = 0; r4 < 64; r4 += 4) {
    int t = t0 + r4 + rr;
    tile[r4 + rr][cc] = V[((size_t)b*SS + t)*64 + cc];
  }
  __syncthreads();
  #pragma unroll
  for (int r4 = 0; r4 < 64; r4 += 4) {
    int vv = r4 + rr;
    VT[((size_t)b*64 + vv)*SS + t0 + cc] = tile[cc][vv];
  }
}

// ---------------- k2c: cross-token dots -> SCL8[4..7] = (kk1,qk1,kk2,qk2)
__global__ __launch_bounds__(256) void crossdot_kernel(
    const float* __restrict__ K, const float* __restrict__ Q,
    float* __restrict__ SCL8) {
  const int tok = blockIdx.x*4 + (threadIdx.x >> 6);
  const int l = threadIdx.x & 63;
  const int tloc = tok & (SS-1);
  const float kt = K[(size_t)tok*64 + l];
  const float qt = Q[(size_t)tok*64 + l];
  const float kp1 = (tloc >= 1) ? K[(size_t)(tok-1)*64 + l] : 0.f;
  const float kp2 = (tloc >= 2) ? K[(size_t)(tok-2)*64 + l] : 0.f;
  float kk1 = wsum(kt*kp1);
  float qk1 = wsum(qt*kp1);
  float kk2 = wsum(kt*kp2);
  float qk2 = wsum(qt*kp2);
  if (l == 0) {
    float4 o; o.x = kk1; o.y = qk1; o.z = kk2; o.w = qk2;
    *(float4*)&SCL8[(size_t)tok*8 + 4] = o;
  }
}

// ---------------- k3: sequential scan, column-parallel, D=2 WY-deferred,
// 4-step register groups pinned by sched_barrier.
// One wave per (b, v). Lane l holds fH[l][v], sH[l][v].
//   pf_t = fa^2*(k_t.fH_{t-3}) + gf_{t-1}*kk1_t + fa*gf_{t-2}*kk2_t
// dff_t = k_t.fH_{t-3} is launched at step t-2 (pre-update fH of that step).
// All per-step operands are in registers loaded one 4-step group earlier;
// sched_barrier(0) fences each {issue | body} so the distance can't collapse.
#define CH 64
__global__ __launch_bounds__(64) void scan_kernel(
    const float* __restrict__ K, const float* __restrict__ Q,
    const float* __restrict__ VT, const float* __restrict__ SCL8,
    const float* __restrict__ fap, const float* __restrict__ sap,
    float* __restrict__ OBASE, float* __restrict__ E) {
  __shared__ float lK[2][CH*64];   // 32 KB
  __shared__ float lQ[2][CH*64];   // 32 KB
  __shared__ float lV[2][CH];      // 512 B
  __shared__ float lS[2][CH*8];    // 4 KB
  const int b = blockIdx.x >> 6;
  const int v = blockIdx.x & 63;
  const int l = threadIdx.x;
  const float fa = *fap, sal = *sap, omfa = 1.f - fa;
  const float fa2 = fa*fa, sa2 = sal*sal;
  const size_t base = (size_t)b * SS * 64;
  const float* gK = K + base + l*4;
  const float* gQ = Q + base + l*4;
  const float* gV = VT + ((size_t)b*64 + v)*SS + l;
  const float* gS = SCL8 + (size_t)b*SS*8 + l*4;
  float* stp = ((l == 32) ? E : OBASE) + base + v;

  float fH = 0.f, sH = 0.f;
  float dff[4] = {0.f,0.f,0.f,0.f}, dqf[4] = {0.f,0.f,0.f,0.f};
  float dss[4] = {0.f,0.f,0.f,0.f}, dqs[4] = {0.f,0.f,0.f,0.f};
  float gf1 = 0.f, gf2 = 0.f, gs1 = 0.f, gs2 = 0.f;
  float  kR[2][4], qR[2][4], vR[2][4];
  float4 aR[2][4], bR[2][4];

#define STAGE(buf, c) {                                              \
    const float* kc_ = gK + (size_t)(c)*CH*64;                       \
    const float* qc_ = gQ + (size_t)(c)*CH*64;                       \
    _Pragma("unroll")                                                \
    for (int j = 0; j < 16; ++j) {                                   \
      gll16(kc_ + j*256, &lK[buf][j*256]);                           \
      gll16(qc_ + j*256, &lQ[buf][j*256]);                           \
    }                                                                \
    gll4(gV + (size_t)(c)*CH, &lV[buf][0]);                          \
    gll16(gS + (size_t)(c)*CH*8,       &lS[buf][0]);                 \
    gll16(gS + (size_t)(c)*CH*8 + 256, &lS[buf][256]); }

#define VMDRAIN { asm volatile("s_waitcnt vmcnt(0)" ::: "memory");   \
                  __builtin_amdgcn_sched_barrier(0); }

  // load token TT (chunk-local, may be >= CH -> next buffer) into set S slot I
#define LOADTOK(S, I, TT) {                                          \
    if ((TT) < CH) {                                                 \
      kR[S][I] = lK[cur][(TT)*64 + l];                               \
      qR[S][I] = lQ[cur][(TT)*64 + l];                               \
      vR[S][I] = lV[cur][(TT)];                                      \
      aR[S][I] = *(const float4*)&lS[cur][(TT)*8];                   \
      bR[S][I] = *(const float4*)&lS[cur][(TT)*8 + 4];               \
    } else {                                                         \
      kR[S][I] = lK[nxt][((TT)-CH)*64 + l];                          \
      qR[S][I] = lQ[nxt][((TT)-CH)*64 + l];                          \
      vR[S][I] = lV[nxt][(TT)-CH];                                   \
      aR[S][I] = *(const float4*)&lS[nxt][((TT)-CH)*8];              \
      bR[S][I] = *(const float4*)&lS[nxt][((TT)-CH)*8 + 4];          \
    } }

  // Step T (chunk-local literal 0..63).
#define STEPX(T) {                                                   \
    const float kf = kR[(((T)+2)>>2)&1][((T)+2)&3];                  \
    const float qf = qR[(((T)+2)>>2)&1][((T)+2)&3];                  \
    const float ndff = wsum(kf*fH), ndqf = wsum(qf*fH);              \
    const float ndss = wsum(kf*sH), ndqs = wsum(qf*sH);              \
    const float  kc = kR[((T)>>2)&1][(T)&3];                         \
    const float  vc = vR[((T)>>2)&1][(T)&3];                         \
    const float4 A  = aR[((T)>>2)&1][(T)&3];                         \
    const float4 Bv = bR[((T)>>2)&1][(T)&3];                         \
    const float agf = fa*gf2, ags = sal*gs2;                         \
    const float pf  = fmaf(fa2, dff[(T)&3], fmaf(gf1, Bv.x, agf*Bv.z)); \
    const float pq  = fmaf(fa2, dqf[(T)&3], fmaf(gf1, Bv.y, agf*Bv.w)); \
    const float ps  = fmaf(sa2, dss[(T)&3], fmaf(gs1, Bv.x, ags*Bv.z)); \
    const float pqs = fmaf(sa2, dqs[(T)&3], fmaf(gs1, Bv.y, ags*Bv.w)); \
    const float gf = omfa*(vc - pf);                                 \
    const float gs = A.y*(vc - ps);                                  \
    const float qfn = fmaf(gf, A.x, fa*pq);                          \
    const float qsn = fmaf(gs, A.x, sal*pqs);                        \
    const float pd = vc - 0.5f*(pq + pqs);                           \
    val[(T)&3] = (l == 32) ? pd*pd : fmaf(A.z, qfn, A.w*qsn);        \
    fH = fmaf(gf, kc, fa*fH);                                        \
    sH = fmaf(gs, kc, sal*sH);                                       \
    gf2 = gf1; gf1 = gf; gs2 = gs1; gs1 = gs;                        \
    dff[((T)+2)&3] = ndff; dqf[((T)+2)&3] = ndqf;                    \
    dss[((T)+2)&3] = ndss; dqs[((T)+2)&3] = ndqs; }

#define GROUP(G) {                                                   \
    LOADTOK((((G)+1)&1), 0, 4*((G)+1)+0)                             \
    LOADTOK((((G)+1)&1), 1, 4*((G)+1)+1)                             \
    LOADTOK((((G)+1)&1), 2, 4*((G)+1)+2)                             \
    LOADTOK((((G)+1)&1), 3, 4*((G)+1)+3)                             \
    __builtin_amdgcn_sched_barrier(0);                               \
    float val[4];                                                    \
    STEPX(4*(G)+0) STEPX(4*(G)+1) STEPX(4*(G)+2) STEPX(4*(G)+3)      \
    if (l == 0 || l == 32) {                                         \
      stp[(size_t)(cbase + 4*(G) + 0)*64] = val[0];                  \
      stp[(size_t)(cbase + 4*(G) + 1)*64] = val[1];                  \
      stp[(size_t)(cbase + 4*(G) + 2)*64] = val[2];                  \
      stp[(size_t)(cbase + 4*(G) + 3)*64] = val[3];                  \
    }                                                                \
    __builtin_amdgcn_sched_barrier(0);                               \
    if ((G) == 14) VMDRAIN }

  STAGE(0, 0)
  VMDRAIN
  int cur = 0, nxt = 1;
  // prime set 0 with chunk-0 tokens 0..3
  #pragma unroll
  for (int i = 0; i < 4; ++i) {
    kR[0][i] = lK[0][i*64 + l];
    qR[0][i] = lQ[0][i*64 + l];
    vR[0][i] = lV[0][i];
    aR[0][i] = *(const float4*)&lS[0][i*8];
    bR[0][i] = *(const float4*)&lS[0][i*8 + 4];
  }
  for (int c = 0; c < 32; ++c) {
    nxt = cur ^ 1;
    if (c + 1 < 32) STAGE(nxt, c + 1)
    const int cbase = c*CH;
    GROUP(0)  GROUP(1)  GROUP(2)  GROUP(3)
    GROUP(4)  GROUP(5)  GROUP(6)  GROUP(7)
    GROUP(8)  GROUP(9)  GROUP(10) GROUP(11)
    GROUP(12) GROUP(13) GROUP(14) GROUP(15)
    cur = nxt;
  }
#undef STAGE
#undef VMDRAIN
#undef LOADTOK
#undef STEPX
#undef GROUP
}

// ---------------- k4: err reduce -> ns-gate coefficient c = 0.1*u_neu
__global__ __launch_bounds__(256) void err_kernel(
    const float* __restrict__ E, float* __restrict__ CNS) {
  int row = blockIdx.x*4 + (threadIdx.x >> 6);
  int l = threadIdx.x & 63;
  float s = wsum(E[(size_t)row*64 + l]);
  if (l == 0) {
    float z = s / (1.0f + 1e-6f);          // TEMP + 1e-6
    float sg = 1.f/(1.f+expf(-z));
    CNS[row] = (sg > 0.7f) ? 0.1f : 0.f;
  }
}

// ---------------- k5: ns scan + o assembly, software-pipelined
#define BW 16
__device__ __forceinline__ void loadw(int b, int t0, int v,
    const float* __restrict__ CNS, const float* __restrict__ NU,
    const float* __restrict__ OBASE, const float* __restrict__ PW,
    float* c, float* nu, float* ob, float* p2) {
  #pragma unroll
  for (int i = 0; i < BW; ++i) {
    size_t bt = (size_t)b*SS + (t0 + i);
    c[i]  = CNS[bt];
    nu[i] = NU[bt*64 + v];
    ob[i] = OBASE[bt*64 + v];
    p2[i] = PW[bt*3 + 2];
  }
}
__device__ __forceinline__ float procw(int b, int t0, int v, float ns,
    const float* c, const float* nu, const float* ob, const float* p2,
    float* __restrict__ OB) {
  #pragma unroll
  for (int i = 0; i < BW; ++i) {
    float cn = c[i]*nu[i];
    float a  = 1.f - c[i];
    ns = fmaf(a, ns, cn);                 // ns = (1-c)*ns + c*nu
    float o = fmaf(p2[i], ns, ob[i]);
    OB[((size_t)b*SS + (t0+i))*64 + v] = o;
  }
  return ns;
}
__global__ __launch_bounds__(64) void nsout_kernel(
    const float* __restrict__ CNS, const float* __restrict__ NU,
    const float* __restrict__ OBASE, const float* __restrict__ PW,
    float* __restrict__ OB) {
  const int b = blockIdx.x, v = threadIdx.x;
  float cA[BW],nA[BW],oA[BW],pA[BW], cB[BW],nB[BW],oB[BW],pB[BW];
  loadw(b, 0, v, CNS, NU, OBASE, PW, cA, nA, oA, pA);
  float ns = 0.f;
  for (int t0 = 0; t0 < SS; t0 += 2*BW) {
    int tB = t0 + BW;
    loadw(b, tB, v, CNS, NU, OBASE, PW, cB, nB, oB, pB);
    ns = procw(b, t0, v, ns, cA, nA, oA, pA, OB);
    int tA2 = t0 + 2*BW; if (tA2 > SS - BW) tA2 = SS - BW;
    loadw(b, tA2, v, CNS, NU, OBASE, PW, cA, nA, oA, pA);
    ns = procw(b, tB, v, ns, cB, nB, oB, pB, OB);
  }
}

// ---------------- k6: fused RMSNorm + out = normed @ Wo^T
__global__ __launch_bounds__(256) void out_gemm(
    const float* __restrict__ OB, const float* __restrict__ Wo,
    const float* __restrict__ normw, float* __restrict__ out) {
  __shared__ float As[64*64];    // [k][m]
  __shared__ float Bs[64*128];   // [k][n]
  const int t  = threadIdx.x;
  const int m0 = blockIdx.y * 64;
  const int n0 = blockIdx.x * 128;
  {
    int r = t >> 2, q4 = t & 3;
    const float* src = OB + (size_t)(m0 + r)*64 + q4*16;
    float4 x0 = ld4(src), x1 = ld4(src+4), x2 = ld4(src+8), x3 = ld4(src+12);
    float ss = x0.x*x0.x+x0.y*x0.y+x0.z*x0.z+x0.w*x0.w
             + x1.x*x1.x+x1.y*x1.y+x1.z*x1.z+x1.w*x1.w
             + x2.x*x2.x+x2.y*x2.y+x2.z*x2.z+x2.w*x2.w
             + x3.x*x3.x+x3.y*x3.y+x3.z*x3.z+x3.w*x3.w;
    ss += __shfl_xor(ss, 1, 64);
    ss += __shfl_xor(ss, 2, 64);
    float rms = rsqrtf(ss * (1.f/64.f) + 1e-6f);
    const float* nw = normw + q4*16;
    float4 w0 = ld4(nw), w1 = ld4(nw+4), w2 = ld4(nw+8), w3 = ld4(nw+12);
    int kbase = q4*16;
    As[(kbase+ 0)*64+r]=x0.x*rms*w0.x; As[(kbase+ 1)*64+r]=x0.y*rms*w0.y;
    As[(kbase+ 2)*64+r]=x0.z*rms*w0.z; As[(kbase+ 3)*64+r]=x0.w*rms*w0.w;
    As[(kbase+ 4)*64+r]=x1.x*rms*w1.x; As[(kbase+ 5)*64+r]=x1.y*rms*w1.y;
    As[(kbase+ 6)*64+r]=x1.z*rms*w1.z; As[(kbase+ 7)*64+r]=x1.w*rms*w1.w;
    As[(kbase+ 8)*64+r]=x2.x*rms*w2.x; As[(kbase+ 9)*64+r]=x2.y*rms*w2.y;
    As[(kbase+10)*64+r]=x2.z*rms*w2.z; As[(kbase+11)*64+r]=x2.w*rms*w2.w;
    As[(kbase+12)*64+r]=x3.x*rms*w3.x; As[(kbase+13)*64+r]=x3.y*rms*w3.y;
    As[(kbase+14)*64+r]=x3.z*rms*w3.z; As[(kbase+15)*64+r]=x3.w*rms*w3.w;
  }
  {
    int rw = t >> 1, half = t & 1;
    const float* src = Wo + (size_t)(n0 + rw)*64 + half*32;
    #pragma unroll
    for (int j = 0; j < 8; ++j) {
      float4 w = ld4(src + j*4);
      int k = half*32 + j*4;
      Bs[(k+0)*128+rw] = w.x; Bs[(k+1)*128+rw] = w.y;
      Bs[(k+2)*128+rw] = w.z; Bs[(k+3)*128+rw] = w.w;
    }
  }
  __syncthreads();
  const int mi = t >> 5, ni = t & 31;
  float acc[8][4];
  #pragma unroll
  for (int i = 0; i < 8; ++i)
    #pragma unroll
    for (int j = 0; j < 4; ++j) acc[i][j] = 0.f;
  #pragma unroll 8
  for (int k = 0; k < 64; ++k) {
    float a[8], bv[4];
    float4 a0 = *(const float4*)&As[k*64 + mi*8];
    float4 a1 = *(const float4*)&As[k*64 + mi*8 + 4];
    float4 b0 = *(const float4*)&Bs[k*128 + ni*4];
    a[0]=a0.x; a[1]=a0.y; a[2]=a0.z; a[3]=a0.w;
    a[4]=a1.x; a[5]=a1.y; a[6]=a1.z; a[7]=a1.w;
    bv[0]=b0.x; bv[1]=b0.y; bv[2]=b0.z; bv[3]=b0.w;
    #pragma unroll
    for (int im = 0; im < 8; ++im)
      #pragma unroll
      for (int in = 0; in < 4; ++in)
        acc[im][in] = fmaf(a[im], bv[in], acc[im][in]);
  }
  #pragma unroll
  for (int im = 0; im < 8; ++im) {
    float4 o; o.x=acc[im][0]; o.y=acc[im][1]; o.z=acc[im][2]; o.w=acc[im][3];
    *(float4*)&out[(size_t)(m0 + mi*8 + im)*1024 + n0 + ni*4] = o;
  }
}

// ---------------- launcher ----------------
extern "C" void kernel_launch(void* const* d_in, const int* in_sizes, int n_in,
                              void* d_out, int out_size, void* d_ws, size_t ws_size,
                              hipStream_t stream) {
  const float* x     = (const float*)d_in[0];
  const float* Wk    = (const float*)d_in[1];
  const float* Wv    = (const float*)d_in[2];
  const float* Wq    = (const float*)d_in[3];
  const float* fap   = (const float*)d_in[4];
  const float* sap   = (const float*)d_in[5];
  const float* nm_w1 = (const float*)d_in[6];
  const float* nm_b1 = (const float*)d_in[7];
  const float* nm_w2 = (const float*)d_in[8];
  const float* nm_b2 = (const float*)d_in[9];
  const float* ir_w1 = (const float*)d_in[10];
  const float* ir_b1 = (const float*)d_in[11];
  const float* ir_w2 = (const float*)d_in[12];
  const float* ir_b2 = (const float*)d_in[13];
  const float* pw    = (const float*)d_in[14];
  const float* Wo    = (const float*)d_in[15];
  const float* normw = (const float*)d_in[16];
  float* out = (float*)d_out;
  float* ws  = (float*)d_ws;

  // workspace layout (floats)
  const size_t oW    = 0;
  const size_t oY    = oW  + (size_t)320*1024;        // Wcat
  const size_t oK    = oY  + (size_t)MM*320;          // Y (reused below)
  const size_t oV    = oK  + (size_t)MM*64;
  const size_t oQ    = oV  + (size_t)MM*64;
  const size_t oNU   = oQ  + (size_t)MM*64;
  const size_t oPW   = oNU + (size_t)MM*64;
  const size_t oSCL  = oPW + (size_t)MM*3;            // SCL8: MM*8
  const size_t oCNS  = oSCL + (size_t)MM*8;
  // Y region reused after post_kernel (Y dead by then):
  const size_t oOBASE = oY;                    // MM*64
  const size_t oE     = oY + (size_t)MM*64;    // MM*64
  const size_t oVT    = oY + (size_t)2*MM*64;  // MM*64
  const size_t oOB    = oY + (size_t)3*MM*64;  // MM*64 (Y region = MM*320, fits)

  pack_w<<<1280, 256, 0, stream>>>(Wk, Wv, Wq, ir_w1, pw, ws + oW);
  gemm1<<<dim3(128, 5), 256, 0, stream>>>(x, ws + oW, ws + oY);
  post_kernel<<<1024, 256, 0, stream>>>(ws + oY, nm_w1, nm_b1, nm_w2, nm_b2,
                                        ir_b1, ir_w2, ir_b2, sap,
                                        ws + oK, ws + oV, ws + oQ, ws + oNU,
                                        ws + oPW, ws + oSCL);
  transpose_v<<<256, 256, 0, stream>>>(ws + oV, ws + oVT);
  crossdot_kernel<<<4096, 256, 0, stream>>>(ws + oK, ws + oQ, ws + oSCL);
  scan_kernel<<<512, 64, 0, stream>>>(ws + oK, ws + oQ, ws + oVT, ws + oSCL,
                                      fap, sap, ws + oOBASE, ws + oE);
  err_kernel<<<4096, 256, 0, stream>>>(ws + oE, ws + oCNS);
  nsout_kernel<<<8, 64, 0, stream>>>(ws + oCNS, ws + oNU, ws + oOBASE,
                                     ws + oPW, ws + oOB);
  out_gemm<<<dim3(8, 256), 256, 0, stream>>>(ws + oOB, Wo, normw, out);
}